// Round 5
// baseline (632.586 us; speedup 1.0000x reference)
//
#include <hip/hip_runtime.h>
#include <math.h>

#define Bn  32
#define Cn  1536
#define Tn  2048
#define BNn 128
#define SHIFT 12.0f

typedef __attribute__((ext_vector_type(8))) short bf16x8;
typedef __attribute__((ext_vector_type(4))) float fx4;

// round-to-nearest-even fp32 -> bf16 (as ushort)
__device__ __forceinline__ unsigned int f2bf1(float f) {
    unsigned int u = __float_as_uint(f);
    return (u + 0x7fffu + ((u >> 16) & 1u)) >> 16;
}
__device__ __forceinline__ float fast_tanh(float v) {
    // 1 - 2/(e^{2v}+1); exact at +-inf saturation, ~1e-6 rel err
    return 1.f - 2.f / (__expf(2.f * v) + 1.f);
}

// ---------------------------------------------------------------------------
// Prep: convert W_tdnn (BN x C) and W_attn (C x BN) fp32 -> bf16.
// ---------------------------------------------------------------------------
__global__ void k_prep(const float* __restrict__ W1f, const float* __restrict__ Waf,
                       short* __restrict__ W1b, short* __restrict__ Wab) {
    int i = blockIdx.x * 256 + threadIdx.x;
    if (i < BNn * Cn) {
        W1b[i] = (short)f2bf1(W1f[i]);
        Wab[i] = (short)f2bf1(Waf[i]);
    }
}

// ---------------------------------------------------------------------------
// Fused kernel. Block = (b, 128-t tile), 256 threads (4 waves, 2x2).
// Phase 1: e-tile = tanh(W1 @ x + b) -> LDS (bf16, swizzled).
// Phase 2: scores via MFMA (A = e-tile regs, B = Wa rows from L2),
// fixed-shift softmax partials, plain sums -> part; k_merge folds.
//
// R5: occupancy 2 -> 3 blocks/CU. __launch_bounds__(256,3) (VGPR cap ~168);
// phase-1 W1 frags loaded per-kt (16 regs); phase-2 processes nt=0,1
// serially (bfr/xq/a2 16 regs each instead of 32). Phase-2 c-order REVERSED
// so the x rows phase 1 read last (L3-hottest) are re-read first.
// ---------------------------------------------------------------------------
__global__ __launch_bounds__(256, 3) void k_fused(
    const float* __restrict__ x, const short* __restrict__ W1,
    const float* __restrict__ bias, const short* __restrict__ Wab,
    const int* __restrict__ mask, float* __restrict__ part)
{
    __shared__ short sA[128 * 64];   // phase-1 x^T staging, ^(t&7) swizzle
    __shared__ short sE[128 * 128];  // e-tile [t][o], ^(t&15) swizzle

    const int b    = blockIdx.y;
    const int t0g  = blockIdx.x * 128;
    const int tid  = threadIdx.x;
    const int lane = tid & 63;
    const int wv   = tid >> 6;
    const int ln   = lane & 15;
    const int g    = lane >> 4;
    const int wt   = (wv & 1) * 64;   // t-half (both phases)
    const int wo   = (wv >> 1) * 64;  // phase-1 o-half

    const float* xb = x + (size_t)b * Cn * Tn;
    const float* xt = xb + t0g;

    const int t4 = (tid & 31) * 4;
    const int cq = (tid >> 5) * 4;

    // ---------------- phase 1: e-tile via MFMA over K=C ----------------
    fx4 acc[4][4];
    #pragma unroll
    for (int i = 0; i < 4; ++i)
        #pragma unroll
        for (int j = 0; j < 4; ++j) acc[i][j] = (fx4){0.f, 0.f, 0.f, 0.f};

    for (int k0 = 0; k0 < Cn; k0 += 64) {
        float4 xr[2][4];
        #pragma unroll
        for (int p = 0; p < 2; ++p) {
            const int c = cq + p * 32;
            #pragma unroll
            for (int j = 0; j < 4; ++j)
                xr[p][j] = *(const float4*)(xt + (size_t)(k0 + c + j) * Tn + t4);
        }
        __syncthreads();
        #pragma unroll
        for (int p = 0; p < 2; ++p) {
            const int c   = cq + p * 32;
            const int blk = c >> 3;
            const int sub = c & 7;
            #pragma unroll
            for (int i = 0; i < 4; ++i) {
                const int t = t4 + i;
                unsigned int lo = f2bf1(((const float*)&xr[p][0])[i]) |
                                  (f2bf1(((const float*)&xr[p][1])[i]) << 16);
                unsigned int hi = f2bf1(((const float*)&xr[p][2])[i]) |
                                  (f2bf1(((const float*)&xr[p][3])[i]) << 16);
                const int idx = t * 64 + ((blk ^ (t & 7)) << 3) + sub;
                *(uint2*)(sA + idx) = make_uint2(lo, hi);
            }
        }
        __syncthreads();

        #pragma unroll
        for (int kt = 0; kt < 2; ++kt) {
            bf16x8 bq[4];   // W1 frags per-kt: 16 VGPR live, not 32
            #pragma unroll
            for (int nn = 0; nn < 4; ++nn)
                bq[nn] = *(const bf16x8*)(W1 + (size_t)(wo + nn * 16 + ln) * Cn
                                          + k0 + kt * 32 + g * 8);
            bf16x8 af[4];
            #pragma unroll
            for (int mm = 0; mm < 4; ++mm) {
                const int t = wt + mm * 16 + ln;
                af[mm] = *(const bf16x8*)(sA + t * 64 + (((kt * 4 + g) ^ (t & 7)) << 3));
            }
            #pragma unroll
            for (int mm = 0; mm < 4; ++mm)
                #pragma unroll
                for (int nn = 0; nn < 4; ++nn)
                    acc[mm][nn] = __builtin_amdgcn_mfma_f32_16x16x32_bf16(
                        af[mm], bq[nn], acc[mm][nn], 0, 0, 0);
        }
    }

    // epilogue: bias + tanh -> sE[t][o], 16B-block swizzle ^(t&15)
    float bs[4];
    #pragma unroll
    for (int nn = 0; nn < 4; ++nn) bs[nn] = bias[wo + nn * 16 + ln];

    #pragma unroll
    for (int mm = 0; mm < 4; ++mm)
        #pragma unroll
        for (int nn = 0; nn < 4; ++nn) {
            #pragma unroll
            for (int r = 0; r < 4; ++r) {
                const int t = wt + mm * 16 + g * 4 + r;
                const int o = wo + nn * 16 + ln;
                const float v = fast_tanh(acc[mm][nn][r] + bs[nn]);
                sE[t * 128 + (((o >> 3) ^ (t & 15)) << 3) + (o & 7)] = (short)f2bf1(v);
            }
        }
    __syncthreads();

    // ---------------- phase 2: scores + stats, barrier-free loop -------
    // A-frags: this wave's 64-t half of the e-tile, K=128, loaded once.
    bf16x8 af2[4][4];
    #pragma unroll
    for (int mt = 0; mt < 4; ++mt)
        #pragma unroll
        for (int kt = 0; kt < 4; ++kt) {
            const int t = wt + mt * 16 + ln;
            af2[mt][kt] = *(const bf16x8*)(sE + t * 128 + (((kt * 4 + g) ^ (t & 15)) << 3));
        }

    // masks for this lane's 16 t's (fixed across c-chunks)
    int4 mv[4];
    #pragma unroll
    for (int mt = 0; mt < 4; ++mt)
        mv[mt] = *(const int4*)(mask + (size_t)b * Tn + t0g + wt + mt * 16 + g * 4);

    const int wc    = (wv >> 1) * 32;            // c-half within 64-chunk
    const int chunk = blockIdx.x * 2 + (wv & 1); // 32 t-half chunks per (b)

    for (int cc = 0; cc < Cn; cc += 64) {
        const int c0 = (Cn - 64) - cc;           // REVERSED: L3-hottest first
        #pragma unroll
        for (int nt = 0; nt < 2; ++nt) {
            const int cr = c0 + wc + nt * 16 + ln;   // this lane's c-row

            bf16x8 bfr[4];                            // Wa row, L2-resident
            #pragma unroll
            for (int kt = 0; kt < 4; ++kt)
                bfr[kt] = *(const bf16x8*)(Wab + (size_t)cr * BNn + kt * 32 + g * 8);

            float4 xq[4];                             // 4 consecutive t each
            #pragma unroll
            for (int mt = 0; mt < 4; ++mt)
                xq[mt] = *(const float4*)(xb + (size_t)cr * Tn
                                          + t0g + wt + mt * 16 + g * 4);

            fx4 a2[4];
            #pragma unroll
            for (int mt = 0; mt < 4; ++mt) a2[mt] = (fx4){0.f, 0.f, 0.f, 0.f};

            #pragma unroll
            for (int kt = 0; kt < 4; ++kt)
                #pragma unroll
                for (int mt = 0; mt < 4; ++mt)
                    a2[mt] = __builtin_amdgcn_mfma_f32_16x16x32_bf16(
                        af2[mt][kt], bfr[kt], a2[mt], 0, 0, 0);

            // fixed-shift softmax partials over this wave's 64 t's
            float s0 = 0.f, s1 = 0.f, s2 = 0.f;
            #pragma unroll
            for (int mt = 0; mt < 4; ++mt) {
                #pragma unroll
                for (int r = 0; r < 4; ++r) {
                    const int msk = ((const int*)&mv[mt])[r];
                    const float p = msk ? 0.f : __expf(a2[mt][r] - SHIFT);
                    const float xv = ((const float*)&xq[mt])[r];
                    s0 += p;
                    s1 += p * xv;
                    s2 += p * xv * xv;
                }
            }
            // fold the 4 g-groups (t-partitions): plain sums, no rescale
            s0 += __shfl_xor(s0, 16); s1 += __shfl_xor(s1, 16); s2 += __shfl_xor(s2, 16);
            s0 += __shfl_xor(s0, 32); s1 += __shfl_xor(s1, 32); s2 += __shfl_xor(s2, 32);
            if (g == 0) {
                *(float4*)&part[(((size_t)b * 32 + chunk) * Cn + cr) * 4] =
                    make_float4(s0, s1, s2, 0.f);
            }
        }
    }
}

// ---------------------------------------------------------------------------
// Merge the 32 t-half-chunk partials per (b,c) -> mean/std output.
// ---------------------------------------------------------------------------
__global__ void k_merge(const float* __restrict__ part, float* __restrict__ out) {
    const int i = blockIdx.x * 256 + threadIdx.x;
    if (i >= Bn * Cn) return;
    const int b = i / Cn, c = i - b * Cn;
    float s0 = 0.f, s1 = 0.f, s2 = 0.f;
    #pragma unroll 8
    for (int sp = 0; sp < 32; ++sp) {
        const float4 v = *(const float4*)&part[(((size_t)b * 32 + sp) * Cn + c) * 4];
        s0 += v.x; s1 += v.y; s2 += v.z;
    }
    const float mean = s1 / s0;
    const float var  = fmaxf(s2 / s0 - mean * mean, 1e-9f);
    out[(size_t)b * (2 * Cn) + c]      = mean;
    out[(size_t)b * (2 * Cn) + Cn + c] = sqrtf(var);
}

extern "C" void kernel_launch(void* const* d_in, const int* in_sizes, int n_in,
                              void* d_out, int out_size, void* d_ws, size_t ws_size,
                              hipStream_t stream) {
    const float* x      = (const float*)d_in[0];
    const int*   mask   = (const int*)d_in[1];
    const float* W_tdnn = (const float*)d_in[2];
    const float* b_tdnn = (const float*)d_in[3];
    const float* W_attn = (const float*)d_in[4];
    // d_in[5] = b_attn: constant over t per row -> cancels in softmax. Unused.
    float* out = (float*)d_out;

    short* W1b  = (short*)d_ws;                     // BN*C bf16
    short* Wab  = W1b + (size_t)BNn * Cn;           // C*BN bf16
    float* part = (float*)(Wab + (size_t)BNn * Cn); // B*32*C*4 f32 = 25.2 MB

    k_prep<<<dim3((BNn * Cn + 255) / 256), 256, 0, stream>>>(W_tdnn, W_attn, W1b, Wab);
    k_fused<<<dim3(Tn / 128, Bn), 256, 0, stream>>>(x, W1b, b_tdnn, Wab, mask, part);
    k_merge<<<dim3((Bn * Cn + 255) / 256), 256, 0, stream>>>(part, out);
}

// Round 6
// 620.835 us; speedup vs baseline: 1.0189x; 1.0189x over previous
//
#include <hip/hip_runtime.h>
#include <math.h>

#define Bn  32
#define Cn  1536
#define Tn  2048
#define BNn 128
#define SHIFT 12.0f

typedef __attribute__((ext_vector_type(8))) short bf16x8;
typedef __attribute__((ext_vector_type(4))) float fx4;

// round-to-nearest-even fp32 -> bf16 (as ushort)
__device__ __forceinline__ unsigned int f2bf1(float f) {
    unsigned int u = __float_as_uint(f);
    return (u + 0x7fffu + ((u >> 16) & 1u)) >> 16;
}
__device__ __forceinline__ float fast_tanh(float v) {
    // 1 - 2/(e^{2v}+1); exact at +-inf saturation, ~1e-6 rel err
    return 1.f - 2.f / (__expf(2.f * v) + 1.f);
}

// ---------------------------------------------------------------------------
// Prep: convert W_tdnn (BN x C) and W_attn (C x BN) fp32 -> bf16.
// ---------------------------------------------------------------------------
__global__ void k_prep(const float* __restrict__ W1f, const float* __restrict__ Waf,
                       short* __restrict__ W1b, short* __restrict__ Wab) {
    int i = blockIdx.x * 256 + threadIdx.x;
    if (i < BNn * Cn) {
        W1b[i] = (short)f2bf1(W1f[i]);
        Wab[i] = (short)f2bf1(Waf[i]);
    }
}

// ---------------------------------------------------------------------------
// Fused kernel. Block = (b, 128-t tile), 256 threads (4 waves, 2x2).
// Phase 1: e-tile = tanh(W1 @ x + b) -> LDS sE (bf16, ^(t&15) swizzle).
// Phase 2: scores via MFMA (A = e-tile regs, B = Wa rows from L2),
// fixed-shift softmax partials (|a| <= ||Wa_c||*||e_t|| <= ~11.3, |e|<1),
// plain sums -> part; k_merge folds the 32 t-half-chunks.
//
// R6: 2-deep software pipelines with NAMED A/B buffers (static reg indexing).
// Phase 1: K-loop unrolled x2; chunk k+1's x loads issue right after the
// post-write barrier, draining a full compute-phase later (was: immediately).
// Phase 2: group i+1's (Wa frags, x quads) prefetched before computing i.
// __launch_bounds__(256,2): R4==R5 showed 2 vs 3 blocks/CU perf-neutral;
// spend the VGPRs on pipeline buffers instead.
// ---------------------------------------------------------------------------

#define P1_LOAD(XR, K0) do {                                                  \
    _Pragma("unroll") for (int p = 0; p < 2; ++p) {                           \
        const int c_ = cq + p * 32;                                           \
        _Pragma("unroll") for (int j = 0; j < 4; ++j)                         \
            XR[p][j] = *(const float4*)(xt + (size_t)((K0) + c_ + j) * Tn + t4); \
    }                                                                         \
} while (0)

#define P1_WRITE(XR) do {                                                     \
    _Pragma("unroll") for (int p = 0; p < 2; ++p) {                           \
        const int c_   = cq + p * 32;                                         \
        const int blk_ = c_ >> 3;                                             \
        const int sub_ = c_ & 7;                                              \
        _Pragma("unroll") for (int i2 = 0; i2 < 4; ++i2) {                    \
            const int t_ = t4 + i2;                                           \
            unsigned int lo_ = f2bf1(((const float*)&XR[p][0])[i2]) |         \
                               (f2bf1(((const float*)&XR[p][1])[i2]) << 16);  \
            unsigned int hi_ = f2bf1(((const float*)&XR[p][2])[i2]) |         \
                               (f2bf1(((const float*)&XR[p][3])[i2]) << 16);  \
            const int idx_ = t_ * 64 + ((blk_ ^ (t_ & 7)) << 3) + sub_;       \
            *(uint2*)(sA + idx_) = make_uint2(lo_, hi_);                      \
        }                                                                     \
    }                                                                         \
} while (0)

#define P1_COMPUTE(K0) do {                                                   \
    _Pragma("unroll") for (int kt = 0; kt < 2; ++kt) {                        \
        bf16x8 bq_[4];                                                        \
        _Pragma("unroll") for (int nn = 0; nn < 4; ++nn)                      \
            bq_[nn] = *(const bf16x8*)(W1 + (size_t)(wo + nn * 16 + ln) * Cn  \
                                       + (K0) + kt * 32 + g * 8);             \
        bf16x8 af_[4];                                                        \
        _Pragma("unroll") for (int mm = 0; mm < 4; ++mm) {                    \
            const int t_ = wt + mm * 16 + ln;                                 \
            af_[mm] = *(const bf16x8*)(sA + t_ * 64                           \
                                       + (((kt * 4 + g) ^ (t_ & 7)) << 3));   \
        }                                                                     \
        _Pragma("unroll") for (int mm = 0; mm < 4; ++mm)                      \
            _Pragma("unroll") for (int nn = 0; nn < 4; ++nn)                  \
                acc[mm][nn] = __builtin_amdgcn_mfma_f32_16x16x32_bf16(        \
                    af_[mm], bq_[nn], acc[mm][nn], 0, 0, 0);                  \
    }                                                                         \
} while (0)

// phase-2 column-group I in [0,48): c0 descending (L3-hottest first)
#define P2_CR(I) (((Cn - 64) - ((I) >> 1) * 64) + wc + ((I) & 1) * 16 + ln)

#define P2_LOAD(BQ, XQ, I) do {                                               \
    const int cr_ = P2_CR(I);                                                 \
    _Pragma("unroll") for (int kt = 0; kt < 4; ++kt)                          \
        BQ[kt] = *(const bf16x8*)(Wab + (size_t)cr_ * BNn + kt * 32 + g * 8); \
    _Pragma("unroll") for (int mt = 0; mt < 4; ++mt)                          \
        XQ[mt] = *(const float4*)(xb + (size_t)cr_ * Tn                       \
                                  + t0g + wt + mt * 16 + g * 4);              \
} while (0)

#define P2_COMPUTE(BQ, XQ, I) do {                                           \
    fx4 a2_[4];                                                               \
    _Pragma("unroll") for (int mt = 0; mt < 4; ++mt)                          \
        a2_[mt] = (fx4){0.f, 0.f, 0.f, 0.f};                                  \
    _Pragma("unroll") for (int kt = 0; kt < 4; ++kt)                          \
        _Pragma("unroll") for (int mt = 0; mt < 4; ++mt)                      \
            a2_[mt] = __builtin_amdgcn_mfma_f32_16x16x32_bf16(                \
                af2[mt][kt], BQ[kt], a2_[mt], 0, 0, 0);                       \
    float s0_ = 0.f, s1_ = 0.f, s2_ = 0.f;                                    \
    _Pragma("unroll") for (int mt = 0; mt < 4; ++mt) {                        \
        _Pragma("unroll") for (int r = 0; r < 4; ++r) {                       \
            const int msk_ = ((const int*)&mv[mt])[r];                        \
            const float p_ = msk_ ? 0.f : __expf(a2_[mt][r] - SHIFT);         \
            const float xv_ = ((const float*)&XQ[mt])[r];                     \
            s0_ += p_; s1_ += p_ * xv_; s2_ += p_ * xv_ * xv_;                \
        }                                                                     \
    }                                                                         \
    s0_ += __shfl_xor(s0_, 16); s1_ += __shfl_xor(s1_, 16);                   \
    s2_ += __shfl_xor(s2_, 16);                                               \
    s0_ += __shfl_xor(s0_, 32); s1_ += __shfl_xor(s1_, 32);                   \
    s2_ += __shfl_xor(s2_, 32);                                               \
    if (g == 0) {                                                             \
        const int cr_ = P2_CR(I);                                             \
        *(float4*)&part[(((size_t)b * 32 + chunk) * Cn + cr_) * 4] =          \
            make_float4(s0_, s1_, s2_, 0.f);                                  \
    }                                                                         \
} while (0)

__global__ __launch_bounds__(256, 2) void k_fused(
    const float* __restrict__ x, const short* __restrict__ W1,
    const float* __restrict__ bias, const short* __restrict__ Wab,
    const int* __restrict__ mask, float* __restrict__ part)
{
    __shared__ short sA[128 * 64];   // phase-1 x^T staging, ^(t&7) swizzle
    __shared__ short sE[128 * 128];  // e-tile [t][o], ^(t&15) swizzle

    const int b    = blockIdx.y;
    const int t0g  = blockIdx.x * 128;
    const int tid  = threadIdx.x;
    const int lane = tid & 63;
    const int wv   = tid >> 6;
    const int ln   = lane & 15;
    const int g    = lane >> 4;
    const int wt   = (wv & 1) * 64;   // t-half (both phases)
    const int wo   = (wv >> 1) * 64;  // phase-1 o-half

    const float* xb = x + (size_t)b * Cn * Tn;
    const float* xt = xb + t0g;

    const int t4 = (tid & 31) * 4;
    const int cq = (tid >> 5) * 4;

    // ---------------- phase 1: e-tile via MFMA over K=C, 2-deep pipe ----
    fx4 acc[4][4];
    #pragma unroll
    for (int i = 0; i < 4; ++i)
        #pragma unroll
        for (int j = 0; j < 4; ++j) acc[i][j] = (fx4){0.f, 0.f, 0.f, 0.f};

    float4 xrA[2][4], xrB[2][4];
    P1_LOAD(xrA, 0);
    for (int k0 = 0; k0 < Cn; k0 += 128) {
        __syncthreads();                    // sA reads of prev chunk done
        P1_WRITE(xrA);
        __syncthreads();
        P1_LOAD(xrB, k0 + 64);              // k0+64 <= 1472 < Cn always
        P1_COMPUTE(k0);                     // loads drain under these MFMAs
        __syncthreads();
        P1_WRITE(xrB);
        __syncthreads();
        if (k0 + 128 < Cn) P1_LOAD(xrA, k0 + 128);
        P1_COMPUTE(k0 + 64);
    }

    // epilogue: bias + tanh -> sE[t][o], 16B-block swizzle ^(t&15)
    float bs[4];
    #pragma unroll
    for (int nn = 0; nn < 4; ++nn) bs[nn] = bias[wo + nn * 16 + ln];

    #pragma unroll
    for (int mm = 0; mm < 4; ++mm)
        #pragma unroll
        for (int nn = 0; nn < 4; ++nn) {
            #pragma unroll
            for (int r = 0; r < 4; ++r) {
                const int t = wt + mm * 16 + g * 4 + r;
                const int o = wo + nn * 16 + ln;
                const float v = fast_tanh(acc[mm][nn][r] + bs[nn]);
                sE[t * 128 + (((o >> 3) ^ (t & 15)) << 3) + (o & 7)] = (short)f2bf1(v);
            }
        }
    __syncthreads();

    // ---------------- phase 2: scores + stats, 2-deep pipe, no barriers -
    // A-frags: this wave's 64-t half of the e-tile, K=128, loaded once.
    bf16x8 af2[4][4];
    #pragma unroll
    for (int mt = 0; mt < 4; ++mt)
        #pragma unroll
        for (int kt = 0; kt < 4; ++kt) {
            const int t = wt + mt * 16 + ln;
            af2[mt][kt] = *(const bf16x8*)(sE + t * 128 + (((kt * 4 + g) ^ (t & 15)) << 3));
        }

    // masks for this lane's 16 t's (fixed across c-chunks)
    int4 mv[4];
    #pragma unroll
    for (int mt = 0; mt < 4; ++mt)
        mv[mt] = *(const int4*)(mask + (size_t)b * Tn + t0g + wt + mt * 16 + g * 4);

    const int wc    = (wv >> 1) * 32;            // c-half within 64-chunk
    const int chunk = blockIdx.x * 2 + (wv & 1); // 32 t-half chunks per (b)

    bf16x8 bA[4], bB[4];
    float4 xA[4], xB[4];
    P2_LOAD(bA, xA, 0);
    for (int i = 0; i < 48; i += 2) {
        P2_LOAD(bB, xB, i + 1);              // prefetch next group
        P2_COMPUTE(bA, xA, i);
        if (i + 2 < 48) P2_LOAD(bA, xA, i + 2);
        P2_COMPUTE(bB, xB, i + 1);
    }
}

// ---------------------------------------------------------------------------
// Merge the 32 t-half-chunk partials per (b,c) -> mean/std output.
// ---------------------------------------------------------------------------
__global__ void k_merge(const float* __restrict__ part, float* __restrict__ out) {
    const int i = blockIdx.x * 256 + threadIdx.x;
    if (i >= Bn * Cn) return;
    const int b = i / Cn, c = i - b * Cn;
    float s0 = 0.f, s1 = 0.f, s2 = 0.f;
    #pragma unroll 8
    for (int sp = 0; sp < 32; ++sp) {
        const float4 v = *(const float4*)&part[(((size_t)b * 32 + sp) * Cn + c) * 4];
        s0 += v.x; s1 += v.y; s2 += v.z;
    }
    const float mean = s1 / s0;
    const float var  = fmaxf(s2 / s0 - mean * mean, 1e-9f);
    out[(size_t)b * (2 * Cn) + c]      = mean;
    out[(size_t)b * (2 * Cn) + Cn + c] = sqrtf(var);
}

extern "C" void kernel_launch(void* const* d_in, const int* in_sizes, int n_in,
                              void* d_out, int out_size, void* d_ws, size_t ws_size,
                              hipStream_t stream) {
    const float* x      = (const float*)d_in[0];
    const int*   mask   = (const int*)d_in[1];
    const float* W_tdnn = (const float*)d_in[2];
    const float* b_tdnn = (const float*)d_in[3];
    const float* W_attn = (const float*)d_in[4];
    // d_in[5] = b_attn: constant over t per row -> cancels in softmax. Unused.
    float* out = (float*)d_out;

    short* W1b  = (short*)d_ws;                     // BN*C bf16
    short* Wab  = W1b + (size_t)BNn * Cn;           // C*BN bf16
    float* part = (float*)(Wab + (size_t)BNn * Cn); // B*32*C*4 f32 = 25.2 MB

    k_prep<<<dim3((BNn * Cn + 255) / 256), 256, 0, stream>>>(W_tdnn, W_attn, W1b, Wab);
    k_fused<<<dim3(Tn / 128, Bn), 256, 0, stream>>>(x, W1b, b_tdnn, Wab, mask, part);
    k_merge<<<dim3((Bn * Cn + 255) / 256), 256, 0, stream>>>(part, out);
}